// Round 4
// baseline (558.472 us; speedup 1.0000x reference)
//
#include <hip/hip_runtime.h>
#include <hip/hip_cooperative_groups.h>
#include <stdint.h>

#pragma clang fp contract(off)

namespace cg = cooperative_groups;
typedef unsigned long long ull;

#define HIGHT 0.7f
#define LOWT  0.3f
#define KSEL  128
#define NBIN  16384        // 14-bit key histogram
#define CAP   2048         // LDS candidate buffer (proof: collected < 128 + nvals/64 <= ~910)
#define MAXGT 512
#define GRD   512          // 2 blocks/CU co-resident (cooperative)
#define TPB   256
#define CHMAX 128          // >= ceil(n1/GRD) = 98
#define NEG1K 0x407FFFFFu  // key32_of_float(-1.0f)
#define LOBIN 7936         // real scores [0,1): bins [8192, 12254) — scan [7936,12288)
#define HIBIN 12288

// ---- total order: descending value, ties -> ascending index (jax top_k) ----
__device__ __forceinline__ unsigned key32_of_float(float f){
  unsigned u = __float_as_uint(f);
  return (u & 0x80000000u) ? ~u : (u | 0x80000000u);
}
__device__ __forceinline__ ull pack_key(unsigned k32, unsigned idx){
  return ((ull)k32 << 32) | (ull)(0xFFFFFFFFu - idx);
}
__device__ __forceinline__ unsigned idx_of_key(ull k){
  return 0xFFFFFFFFu - (unsigned)(k & 0xFFFFFFFFull);
}

// ---- bit-exact IoU (numpy fp32 op-for-op; no contraction; IEEE div) ----
__device__ __forceinline__ float iou_pair(float ax0, float ay0, float ax1, float ay1, float aarea,
                                          float bx0, float by0, float bx1, float by1, float barea){
#pragma clang fp contract(off)
  float x0 = fmaxf(ax0, bx0);
  float y0 = fmaxf(ay0, by0);
  float x1 = fminf(ax1, bx1);
  float y1 = fminf(ay1, by1);
  float dx = fmaxf(x1 - x0, 0.0f);
  float dy = fmaxf(y1 - y0, 0.0f);
  float inter = dx * dy;
  float uni = (aarea + barea) - inter;
  return inter / uni;
}

__device__ __forceinline__ ull shfl_xor_u64(ull v, int m){
  int lo = __shfl_xor((int)(unsigned)(v & 0xFFFFFFFFull), m, 64);
  int hi = __shfl_xor((int)(unsigned)(v >> 32), m, 64);
  return ((ull)(unsigned)hi << 32) | (unsigned)lo;
}

__global__ __launch_bounds__(TPB, 2)
void mega_kernel(const float4* __restrict__ boxes, const float4* __restrict__ gts,
                 const float* __restrict__ pn, const float* __restrict__ nn,
                 int n1, int n2,
                 float* __restrict__ max_iou, int* __restrict__ input_idx,
                 ull* __restrict__ colpart, unsigned char* __restrict__ forced,
                 int* __restrict__ hist, int* __restrict__ neg_count,
                 int* __restrict__ out)
{
#pragma clang fp contract(off)
  cg::grid_group grid = cg::this_grid();
  const int b = blockIdx.x, t = threadIdx.x;
  const int B = gridDim.x;

  __shared__ float4 gc[MAXGT];
  __shared__ float  ga[MAXGT];
  __shared__ float4 pc[CHMAX];
  __shared__ float  pa_s[CHMAX];
  __shared__ ull    keys[CAP];     // phase-2 reduce scratch + phase-4 candidates
  __shared__ int    s_cnt, s_bstar, s_tot;

  // ---- phase 0: distributed zero (ordered before use by sync #1)
  {
    const int histn = 3 * NBIN;
    for (int x = b * TPB + t; x < histn; x += B * TPB) hist[x] = 0;
    const int fw = (n1 + 3) >> 2;
    unsigned* fwp = (unsigned*)forced;
    for (int x = b * TPB + t; x < fw; x += B * TPB) fwp[x] = 0u;
    if (b == 0 && t == 0) *neg_count = 0;
  }

  // ---- phase 1a: stage GT corners in LDS
  for (int j = t; j < n2; j += TPB){
    float4 g = gts[j];
    float hw = g.z * 0.5f, hh = g.w * 0.5f;
    gc[j] = make_float4(g.x - hw, g.y - hh, g.x + hw, g.y + hh);
    ga[j] = g.z * g.w;
  }
  __syncthreads();

  const int chunk = (n1 + B - 1) / B;             // 98
  const int lo = b * chunk;
  int cr = n1 - lo; if (cr > chunk) cr = chunk; if (cr < 0) cr = 0;
  const int chunkR = cr;

  // ---- phase 1b: row max/argmax — 2 threads/proposal, halves merged via shfl
  {
    int pi = t >> 1, half = t & 1;
    int i = lo + pi;
    bool valid = (pi < chunkR);
    ull rbest = 0;
    float px0 = 0, py0 = 0, px1 = 0, py1 = 0, pa = 0;
    if (valid){
      float4 pb = boxes[i];
      float hw = pb.z * 0.5f, hh = pb.w * 0.5f;
      px0 = pb.x - hw; py0 = pb.y - hh; px1 = pb.x + hw; py1 = pb.y + hh;
      pa = pb.z * pb.w;
      int jlo = half * (n2 >> 1), jhi = jlo + (n2 >> 1);
      #pragma unroll 4
      for (int j = jlo; j < jhi; ++j){
        float4 g = gc[j];
        float v = iou_pair(px0, py0, px1, py1, pa, g.x, g.y, g.z, g.w, ga[j]);
        ull key = pack_key(key32_of_float(v), (unsigned)j);
        if (key > rbest) rbest = key;
      }
    }
    ull o = shfl_xor_u64(rbest, 1);
    if (o > rbest) rbest = o;
    if (valid && half == 0){
      unsigned k32 = (unsigned)(rbest >> 32);
      float v = (k32 & 0x80000000u) ? __uint_as_float(k32 & 0x7FFFFFFFu)
                                    : __uint_as_float(~k32);
      max_iou[i] = v;
      input_idx[i] = (int)idx_of_key(rbest);
      pc[pi] = make_float4(px0, py0, px1, py1);   // stage corners for col pass
      pa_s[pi] = pa;
    }
  }
  __syncthreads();

  // ---- phase 1c: col partials — thread t handles GTs t, t+256 over block's chunk
  for (int jj = t; jj < n2; jj += TPB){
    float4 gv = gc[jj]; float gav = ga[jj];
    ull cb = 0;
    for (int p = 0; p < chunkR; ++p){
      float4 pv = pc[p];                           // wave-uniform -> LDS broadcast
      float v = iou_pair(pv.x, pv.y, pv.z, pv.w, pa_s[p],
                         gv.x, gv.y, gv.z, gv.w, gav);
      ull key = pack_key(key32_of_float(v), (unsigned)(lo + p));
      if (key > cb) cb = key;
    }
    colpart[(size_t)jj * B + b] = cb;
  }

  __threadfence();
  grid.sync();

  // ---- phase 2: col reduce + forced scatter (block j <-> GT j)
  if (b < n2){
    ull m = 0;
    for (int x = t; x < B; x += TPB){
      ull v = colpart[(size_t)b * B + x];
      if (v > m) m = v;
    }
    keys[t] = m;
    __syncthreads();
    for (int s = TPB >> 1; s > 0; s >>= 1){
      if (t < s && keys[t + s] > keys[t]) keys[t] = keys[t + s];
      __syncthreads();
    }
    if (t == 0) forced[idx_of_key(keys[0])] = 1;
  }

  __threadfence();
  grid.sync();

  // ---- phase 3: histograms (real scores only!) + neg_count
  for (int x = lo + t; x < lo + chunkR; x += TPB){
    float m = max_iou[x];
    bool f = forced[x] != 0;
    bool pos = (m > HIGHT) || f;
    if (pos) atomicAdd(&hist[key32_of_float(pn[x]) >> 18], 1);
    unsigned kn = key32_of_float(nn[x]);
    bool nm = (m < LOWT) && !f;
    if (nm){ atomicAdd(&hist[NBIN + (kn >> 18)], 1); atomicAdd(neg_count, 1); }
    if (!pos) atomicAdd(&hist[2 * NBIN + (kn >> 18)], 1);
  }

  __threadfence();
  grid.sync();

  // ---- phase 4 (blocks 0/1): thresh scan + collect + rank-select + output
  if (b >= 2) return;
  const bool isPos = (b == 0);
  bool fb = false;
  const int* h;
  if (isPos) h = hist;
  else { fb = (*neg_count == 0); h = fb ? (hist + 2 * NBIN) : (hist + NBIN); }
  if (t == 0) s_cnt = 0;

  if (t < 64){
    // single-wave descending suffix scan, 256 bins per iteration
    int lane = t;
    int cum = 0, fbin = -1;
    for (int base = HIBIN - 256; base >= LOBIN; base -= 256){
      int4 v = *(const int4*)(h + base + 4 * lane);  // lane covers 4 ascending bins
      int s = v.x + v.y + v.z + v.w;
      int incl = s;
      #pragma unroll
      for (int off = 1; off < 64; off <<= 1){
        int o = __shfl_down(incl, off, 64);
        if (lane + off < 64) incl += o;
      }
      int tot = __shfl(incl, 0, 64);                 // chunk total
      int sa = cum + (incl - s);                     // suffix strictly above my 4 bins
      int w3 = v.w, w2 = w3 + v.z, w1 = w2 + v.y, w0 = w1 + v.x;
      int f = -1;
      if      (sa + w3 >= KSEL && sa      < KSEL) f = base + 4 * lane + 3;
      else if (sa + w2 >= KSEL && sa + w3 < KSEL) f = base + 4 * lane + 2;
      else if (sa + w1 >= KSEL && sa + w2 < KSEL) f = base + 4 * lane + 1;
      else if (sa + w0 >= KSEL && sa + w1 < KSEL) f = base + 4 * lane + 0;
      ull bal = __ballot(f >= 0);
      if (bal != 0ull){
        int ln = (int)__ffsll((long long)bal) - 1;
        fbin = __shfl(f, ln, 64);
        break;
      }
      cum += tot;
    }
    if (lane == 0){
      s_bstar = (fbin >= 0) ? fbin : 0;
      s_tot = (fbin >= 0) ? KSEL : cum;   // exact total only when < KSEL
    }
  }
  __syncthreads();
  const int bst = s_bstar, tot = s_tot;

  // collect candidates into LDS
  for (int i = t; i < n1; i += TPB){
    float m = max_iou[i];
    bool f = forced[i] != 0;
    bool pos = (m > HIGHT) || f;
    bool sel; unsigned k32 = 0;
    if (isPos){ sel = pos; if (sel) k32 = key32_of_float(pn[i]); }
    else { sel = fb ? (!pos) : ((m < LOWT) && !f); if (sel) k32 = key32_of_float(nn[i]); }
    if (sel){
      if ((int)(k32 >> 18) >= bst){
        int p = atomicAdd(&s_cnt, 1);
        if (p < CAP) keys[p] = pack_key(k32, (unsigned)i);
      }
    } else if (tot < KSEL && i < 2 * KSEL){
      // fewer than 128 real candidates: ref top_k picks -1-scored entries by
      // ascending index; the needed fills all have index < 2*KSEL
      int p = atomicAdd(&s_cnt, 1);
      if (p < CAP) keys[p] = pack_key(NEG1K, (unsigned)i);
    }
  }
  __syncthreads();
  int n = s_cnt; if (n > CAP) n = CAP;

  // exact rank-select (keys totally ordered & unique)
  ull mykey[8]; int myrank[8]; int ne = 0;
  for (int x = t; x < n; x += TPB){ mykey[ne] = keys[x]; myrank[ne] = 0; ++ne; }
  for (int o = 0; o < n; ++o){
    ull ko = keys[o];
    #pragma unroll
    for (int e = 0; e < 8; ++e)
      if (e < ne && ko > mykey[e]) myrank[e]++;
  }
  for (int e = 0; e < ne; ++e){
    int r = myrank[e];
    if (r < KSEL){
      unsigned idx = idx_of_key(mykey[e]);
      if (isPos){ out[r] = (int)idx; out[KSEL + r] = input_idx[idx]; }
      else        out[2 * KSEL + r] = (int)idx;
    }
  }
}

extern "C" void kernel_launch(void* const* d_in, const int* in_sizes, int n_in,
                              void* d_out, int out_size, void* d_ws, size_t ws_size,
                              hipStream_t stream){
  const float4* boxes = (const float4*)d_in[0];
  const float4* gts   = (const float4*)d_in[1];
  const float* pos_noise = (const float*)d_in[2];
  const float* neg_noise = (const float*)d_in[3];
  int n1 = in_sizes[0] / 4;
  int n2 = in_sizes[1] / 4;
  int* out = (int*)d_out;

  char* ws = (char*)d_ws;
  size_t off = 0;
  auto carve = [&](size_t bytes) -> char* {
    char* p = ws + off;
    off = (off + bytes + 255) & ~(size_t)255;
    return p;
  };
  float* max_iou   = (float*)carve((size_t)n1 * 4);
  int*   input_idx = (int*)  carve((size_t)n1 * 4);
  ull*   colpart   = (ull*)  carve((size_t)n2 * GRD * 8);
  unsigned char* forced = (unsigned char*)carve(((size_t)n1 + 3) & ~(size_t)3);
  int*   hist      = (int*)  carve((size_t)3 * NBIN * 4);
  int*   neg_count = (int*)  carve(4);

  void* args[] = {
    (void*)&boxes, (void*)&gts, (void*)&pos_noise, (void*)&neg_noise,
    (void*)&n1, (void*)&n2,
    (void*)&max_iou, (void*)&input_idx, (void*)&colpart, (void*)&forced,
    (void*)&hist, (void*)&neg_count, (void*)&out
  };
  hipLaunchCooperativeKernel((void*)mega_kernel, dim3(GRD), dim3(TPB),
                             args, 0, stream);
}

// Round 5
// 210.783 us; speedup vs baseline: 2.6495x; 2.6495x over previous
//
#include <hip/hip_runtime.h>
#include <stdint.h>

#pragma clang fp contract(off)

typedef unsigned long long ull;

#define HIGHT 0.7f
#define LOWT  0.3f
#define KSEL  128
#define NBIN  16384        // 14-bit key histogram
#define CAP   2048         // LDS candidate buffer (collected < 128 + maxbin, or <= 384 in fill case)
#define MAXGT 512
#define TPB   256
#define CHUNK 64           // proposals per fused_iou block
#define NEG1K 0x407FFFFFu  // key32_of_float(-1.0f)
#define LOBIN 7936         // real scores [0,1): bins [8192,12256) — scan [7936,12288)
#define HIBIN 12288

// ---- total order: descending value, ties -> ascending index (jax top_k) ----
__device__ __forceinline__ unsigned key32_of_float(float f){
  unsigned u = __float_as_uint(f);
  return (u & 0x80000000u) ? ~u : (u | 0x80000000u);
}
__device__ __forceinline__ ull pack_key(unsigned k32, unsigned idx){
  return ((ull)k32 << 32) | (ull)(0xFFFFFFFFu - idx);
}
__device__ __forceinline__ unsigned idx_of_key(ull k){
  return 0xFFFFFFFFu - (unsigned)(k & 0xFFFFFFFFull);
}

// ---- bit-exact IoU (numpy fp32 op-for-op; no contraction; IEEE div) ----
__device__ __forceinline__ float iou_pair(float ax0, float ay0, float ax1, float ay1, float aarea,
                                          float bx0, float by0, float bx1, float by1, float barea){
#pragma clang fp contract(off)
  float x0 = fmaxf(ax0, bx0);
  float y0 = fmaxf(ay0, by0);
  float x1 = fminf(ax1, bx1);
  float y1 = fminf(ay1, by1);
  float dx = fmaxf(x1 - x0, 0.0f);
  float dy = fmaxf(y1 - y0, 0.0f);
  float inter = dx * dy;
  float uni = (aarea + barea) - inter;
  return inter / uni;
}

__device__ __forceinline__ ull shfl_xor_u64(ull v, int m){
  int lo = __shfl_xor((int)(unsigned)(v & 0xFFFFFFFFull), m, 64);
  int hi = __shfl_xor((int)(unsigned)(v >> 32), m, 64);
  return ((ull)(unsigned)hi << 32) | (unsigned)lo;
}

// ---- K1: zero scratch + row max/argmax + col partials (corners staged in LDS) ----
__global__ __launch_bounds__(TPB)
void fused_iou(const float4* __restrict__ boxes, const float4* __restrict__ gts,
               int n1, int n2, int nblk,
               float* __restrict__ max_iou, int* __restrict__ input_idx,
               ull* __restrict__ colpart, unsigned* __restrict__ forcedw,
               int* __restrict__ hist, int* __restrict__ neg_count)
{
#pragma clang fp contract(off)
  const int b = blockIdx.x, t = threadIdx.x;

  // distributed zeroing (consumed only by later kernels; stream order suffices)
  {
    const int histn = 3 * NBIN;
    for (int x = b * TPB + t; x < histn; x += nblk * TPB) hist[x] = 0;
    const int fw = (n1 + 3) >> 2;
    for (int x = b * TPB + t; x < fw; x += nblk * TPB) forcedw[x] = 0u;
    if (b == 0 && t == 0) *neg_count = 0;
  }

  __shared__ float4 gc[MAXGT];
  __shared__ float  ga[MAXGT];
  __shared__ float4 pc[CHUNK];
  __shared__ float  pa_s[CHUNK];

  for (int j = t; j < n2; j += TPB){
    float4 g = gts[j];
    float hw = g.z * 0.5f, hh = g.w * 0.5f;
    gc[j] = make_float4(g.x - hw, g.y - hh, g.x + hw, g.y + hh);
    ga[j] = g.z * g.w;
  }
  __syncthreads();

  const int lo = b * CHUNK;
  int cr = n1 - lo; if (cr > CHUNK) cr = CHUNK; if (cr < 0) cr = 0;

  // row pass: 4 threads/proposal; quarter q reads j = q, q+4, ... (interleaved
  // -> the 4 quarters hit 4 CONSECUTIVE float4s per step: disjoint banks,
  //    16-lane broadcast each — conflict-free; blocked ranges alias banks)
  {
    const int pi = t >> 2, q = t & 3;
    const bool valid = (pi < cr);
    ull rb = 0;
    float px0 = 0, py0 = 0, px1 = 0, py1 = 0, pa = 0;
    if (valid){
      float4 pb = boxes[lo + pi];
      float hw = pb.z * 0.5f, hh = pb.w * 0.5f;
      px0 = pb.x - hw; py0 = pb.y - hh; px1 = pb.x + hw; py1 = pb.y + hh;
      pa = pb.z * pb.w;
      #pragma unroll 4
      for (int j = q; j < n2; j += 4){
        float4 g = gc[j];
        float v = iou_pair(px0, py0, px1, py1, pa, g.x, g.y, g.z, g.w, ga[j]);
        ull key = pack_key(key32_of_float(v), (unsigned)j);   // exact first-max tie-break
        if (key > rb) rb = key;
      }
    }
    ull o = shfl_xor_u64(rb, 1); if (o > rb) rb = o;
    o = shfl_xor_u64(rb, 2);     if (o > rb) rb = o;
    if (valid && q == 0){
      unsigned k32 = (unsigned)(rb >> 32);
      float v = (k32 & 0x80000000u) ? __uint_as_float(k32 & 0x7FFFFFFFu)
                                    : __uint_as_float(~k32);
      max_iou[lo + pi] = v;
      input_idx[lo + pi] = (int)idx_of_key(rb);
      pc[pi] = make_float4(px0, py0, px1, py1);
      pa_s[pi] = pa;
    }
  }
  __syncthreads();

  // col pass: thread t owns GTs t and t+256 (registers); pc[p] is wave-uniform
  {
    float4 g1 = make_float4(0,0,0,0), g2 = make_float4(0,0,0,0);
    float a1 = 0, a2 = 0;
    const bool v1 = (t < n2), v2 = (t + TPB < n2);
    if (v1){ g1 = gc[t];        a1 = ga[t]; }
    if (v2){ g2 = gc[t + TPB];  a2 = ga[t + TPB]; }
    ull c1 = 0, c2 = 0;
    for (int p = 0; p < cr; ++p){
      float4 pv = pc[p]; float pav = pa_s[p];
      if (v1){
        float v = iou_pair(pv.x, pv.y, pv.z, pv.w, pav, g1.x, g1.y, g1.z, g1.w, a1);
        ull k = pack_key(key32_of_float(v), (unsigned)(lo + p));
        if (k > c1) c1 = k;
      }
      if (v2){
        float v = iou_pair(pv.x, pv.y, pv.z, pv.w, pav, g2.x, g2.y, g2.z, g2.w, a2);
        ull k = pack_key(key32_of_float(v), (unsigned)(lo + p));
        if (k > c2) c2 = k;
      }
    }
    if (v1) colpart[(size_t)b * n2 + t] = c1;        // coalesced
    if (v2) colpart[(size_t)b * n2 + t + TPB] = c2;
  }
}

// ---- K2: per-GT reduce over block partials + forced scatter ----
__global__ __launch_bounds__(TPB)
void colreduce(const ull* __restrict__ colpart, int n2, int nblk,
               unsigned char* __restrict__ forced)
{
  const int jj = blockIdx.x, t = threadIdx.x;
  ull m = 0;
  for (int x = t; x < nblk; x += TPB){
    ull v = colpart[(size_t)x * n2 + jj];
    if (v > m) m = v;
  }
  __shared__ ull red[TPB];
  red[t] = m;
  __syncthreads();
  for (int s = TPB >> 1; s > 0; s >>= 1){
    if (t < s && red[t + s] > red[t]) red[t] = red[t + s];
    __syncthreads();
  }
  if (t == 0) forced[idx_of_key(red[0])] = 1;
}

// ---- K3: histograms (real scores only) + block-reduced neg_count ----
__global__ __launch_bounds__(TPB)
void hist_kernel(const float* __restrict__ max_iou, const unsigned char* __restrict__ forced,
                 const float* __restrict__ pn, const float* __restrict__ nn,
                 int n1, int* __restrict__ hist, int* __restrict__ neg_count)
{
  __shared__ int s_neg;
  const int t = threadIdx.x;
  if (t == 0) s_neg = 0;
  __syncthreads();
  const int i = blockIdx.x * TPB + t;
  if (i < n1){
    float m = max_iou[i];
    bool f = forced[i] != 0;
    bool pos = (m > HIGHT) || f;
    unsigned kn = key32_of_float(nn[i]);
    if (pos) atomicAdd(&hist[key32_of_float(pn[i]) >> 18], 1);
    bool nm = (m < LOWT) && !f;
    if (nm){ atomicAdd(&hist[NBIN + (kn >> 18)], 1); atomicAdd(&s_neg, 1); }
    if (!pos) atomicAdd(&hist[2 * NBIN + (kn >> 18)], 1);
  }
  __syncthreads();
  if (t == 0 && s_neg > 0) atomicAdd(neg_count, s_neg);
}

// ---- K4: per-mode block: threshold scan + collect + exact rank-select + out ----
__global__ __launch_bounds__(1024)
void final_kernel(const float* __restrict__ max_iou, const unsigned char* __restrict__ forced,
                  const float* __restrict__ pn, const float* __restrict__ nn,
                  int n1, const int* __restrict__ hist, const int* __restrict__ neg_count,
                  const int* __restrict__ input_idx, int* __restrict__ out)
{
  const int t = threadIdx.x;
  const bool isPos = (blockIdx.x == 0);
  __shared__ ull keys[CAP];
  __shared__ int s_cnt, s_bstar, s_tot, s_fb;
  if (t == 0){
    s_cnt = 0;
    s_fb = (!isPos && *neg_count == 0) ? 1 : 0;
  }
  __syncthreads();
  const bool fb = (s_fb != 0);
  const int* h = isPos ? hist : (fb ? hist + 2 * NBIN : hist + NBIN);

  if (t < 64){
    // single-wave descending suffix scan, 256 bins per iteration
    int lane = t;
    int cum = 0, fbin = -1;
    for (int base = HIBIN - 256; base >= LOBIN; base -= 256){
      int4 v = *(const int4*)(h + base + 4 * lane);
      int s = v.x + v.y + v.z + v.w;
      int incl = s;
      #pragma unroll
      for (int off = 1; off < 64; off <<= 1){
        int o = __shfl_down(incl, off, 64);
        if (lane + off < 64) incl += o;
      }
      int ctot = __shfl(incl, 0, 64);
      int sa = cum + (incl - s);                  // suffix strictly above my 4 bins
      int w3 = v.w, w2 = w3 + v.z, w1 = w2 + v.y, w0 = w1 + v.x;
      int f = -1;
      if      (sa + w3 >= KSEL && sa      < KSEL) f = base + 4 * lane + 3;
      else if (sa + w2 >= KSEL && sa + w3 < KSEL) f = base + 4 * lane + 2;
      else if (sa + w1 >= KSEL && sa + w2 < KSEL) f = base + 4 * lane + 1;
      else if (sa + w0 >= KSEL && sa + w1 < KSEL) f = base + 4 * lane + 0;
      ull bal = __ballot(f >= 0);
      if (bal != 0ull){
        int ln = (int)__ffsll((long long)bal) - 1;
        fbin = __shfl(f, ln, 64);
        break;
      }
      cum += ctot;
    }
    if (lane == 0){
      s_bstar = (fbin >= 0) ? fbin : 0;
      s_tot = (fbin >= 0) ? KSEL : cum;           // exact total only when < KSEL
    }
  }
  __syncthreads();
  const int bst = s_bstar, tot = s_tot;

  // collect candidates into LDS
  for (int i = t; i < n1; i += 1024){
    float m = max_iou[i];
    bool f = forced[i] != 0;
    bool pos = (m > HIGHT) || f;
    bool sel; unsigned k32 = 0;
    if (isPos){ sel = pos; if (sel) k32 = key32_of_float(pn[i]); }
    else { sel = fb ? (!pos) : ((m < LOWT) && !f); if (sel) k32 = key32_of_float(nn[i]); }
    if (sel){
      if ((int)(k32 >> 18) >= bst){
        int p = atomicAdd(&s_cnt, 1);
        if (p < CAP) keys[p] = pack_key(k32, (unsigned)i);
      }
    } else if (tot < KSEL && i < 2 * KSEL){
      // fewer than 128 real candidates: ref top_k fills with -1-scored entries
      // in ascending index; needed fills all have index < 2*KSEL
      int p = atomicAdd(&s_cnt, 1);
      if (p < CAP) keys[p] = pack_key(NEG1K, (unsigned)i);
    }
  }
  __syncthreads();
  int n = s_cnt; if (n > CAP) n = CAP;

  // exact rank-select (keys totally ordered & unique)
  ull mk[2]; int mr[2]; int ne = 0;
  for (int x = t; x < n; x += 1024){ mk[ne] = keys[x]; mr[ne] = 0; ++ne; }
  for (int o = 0; o < n; ++o){
    ull ko = keys[o];                              // uniform addr -> LDS broadcast
    if (ne > 0) mr[0] += (ko > mk[0]);
    if (ne > 1) mr[1] += (ko > mk[1]);
  }
  for (int e = 0; e < ne; ++e){
    int r = mr[e];
    if (r < KSEL){
      unsigned idx = idx_of_key(mk[e]);
      if (isPos){ out[r] = (int)idx; out[KSEL + r] = input_idx[idx]; }
      else        out[2 * KSEL + r] = (int)idx;
    }
  }
}

extern "C" void kernel_launch(void* const* d_in, const int* in_sizes, int n_in,
                              void* d_out, int out_size, void* d_ws, size_t ws_size,
                              hipStream_t stream){
  const float4* boxes = (const float4*)d_in[0];
  const float4* gts   = (const float4*)d_in[1];
  const float* pos_noise = (const float*)d_in[2];
  const float* neg_noise = (const float*)d_in[3];
  const int n1 = in_sizes[0] / 4;
  const int n2 = in_sizes[1] / 4;
  int* out = (int*)d_out;

  char* ws = (char*)d_ws;
  size_t off = 0;
  auto carve = [&](size_t bytes) -> char* {
    char* p = ws + off;
    off = (off + bytes + 255) & ~(size_t)255;
    return p;
  };
  const int nblk = (n1 + CHUNK - 1) / CHUNK;       // 782
  float* max_iou   = (float*)carve((size_t)n1 * 4);
  int*   input_idx = (int*)  carve((size_t)n1 * 4);
  ull*   colpart   = (ull*)  carve((size_t)nblk * n2 * 8);
  unsigned char* forced = (unsigned char*)carve(((size_t)n1 + 3) & ~(size_t)3);
  int*   hist      = (int*)  carve((size_t)3 * NBIN * 4);
  int*   neg_count = (int*)  carve(4);

  fused_iou<<<nblk, TPB, 0, stream>>>(boxes, gts, n1, n2, nblk,
                                      max_iou, input_idx, colpart,
                                      (unsigned*)forced, hist, neg_count);
  colreduce<<<n2, TPB, 0, stream>>>(colpart, n2, nblk, forced);
  hist_kernel<<<(n1 + TPB - 1) / TPB, TPB, 0, stream>>>(max_iou, forced, pos_noise, neg_noise,
                                                        n1, hist, neg_count);
  final_kernel<<<2, 1024, 0, stream>>>(max_iou, forced, pos_noise, neg_noise,
                                       n1, hist, neg_count, input_idx, out);
}

// Round 7
// 204.401 us; speedup vs baseline: 2.7322x; 1.0312x over previous
//
#include <hip/hip_runtime.h>
#include <stdint.h>

#pragma clang fp contract(off)

typedef unsigned long long ull;

#define HIGHT 0.7f
#define LOWT  0.3f
#define KSEL  128
#define CAP   2048         // LDS candidate buffer
#define MAXGT 512
#define TPB   256
#define CHUNK 64           // proposals per fused_iou block
#define NLAD  7            // adaptive threshold ladder

// ---- bit-exact IoU (numpy fp32 op-for-op; no contraction; IEEE div) ----
__device__ __forceinline__ float iou_pair(float ax0, float ay0, float ax1, float ay1, float aarea,
                                          float bx0, float by0, float bx1, float by1, float barea){
#pragma clang fp contract(off)
  float x0 = fmaxf(ax0, bx0);
  float y0 = fmaxf(ay0, by0);
  float x1 = fminf(ax1, bx1);
  float y1 = fminf(ay1, by1);
  float dx = fmaxf(x1 - x0, 0.0f);
  float dy = fmaxf(y1 - y0, 0.0f);
  float inter = dx * dy;
  float uni = (aarea + barea) - inter;
  return inter / uni;
}

// ---- K1: zero forced + row max/argmax + col partials (corners staged in LDS) ----
__global__ __launch_bounds__(TPB)
void fused_iou(const float4* __restrict__ boxes, const float4* __restrict__ gts,
               int n1, int n2, int nblk,
               float* __restrict__ max_iou, int* __restrict__ input_idx,
               ull* __restrict__ colpart, unsigned* __restrict__ forcedw)
{
#pragma clang fp contract(off)
  const int b = blockIdx.x, t = threadIdx.x;

  // distributed zeroing of forced flags (consumed by later kernels)
  {
    const int fw = (n1 + 3) >> 2;
    for (int x = b * TPB + t; x < fw; x += nblk * TPB) forcedw[x] = 0u;
  }

  __shared__ float4 gc[MAXGT];
  __shared__ float  ga[MAXGT];
  __shared__ float4 pc[CHUNK];
  __shared__ float  pa_s[CHUNK];

  for (int j = t; j < n2; j += TPB){
    float4 g = gts[j];
    float hw = g.z * 0.5f, hh = g.w * 0.5f;
    gc[j] = make_float4(g.x - hw, g.y - hh, g.x + hw, g.y + hh);
    ga[j] = g.z * g.w;
  }
  __syncthreads();

  const int lo = b * CHUNK;
  int cr = n1 - lo; if (cr > CHUNK) cr = CHUNK; if (cr < 0) cr = 0;

  // row pass: 4 threads/proposal, quarter q owns j = q, q+4, ...; split into
  // TWO independent chains (j and j+4 step 8) to overlap div latency.
  // IoU >= 0 never NaN; strict > with ascending j = first-occurrence argmax.
  {
    const int pi = t >> 2, q = t & 3;
    const bool valid = (pi < cr);
    float vA = -1.0f, vB = -1.0f; int jA = 0, jB = 0;
    float px0 = 0, py0 = 0, px1 = 0, py1 = 0, pa = 0;
    if (valid){
      float4 pb = boxes[lo + pi];
      float hw = pb.z * 0.5f, hh = pb.w * 0.5f;
      px0 = pb.x - hw; py0 = pb.y - hh; px1 = pb.x + hw; py1 = pb.y + hh;
      pa = pb.z * pb.w;
      int j = q;
      for (; j + 4 < n2; j += 8){
        float4 g0 = gc[j];     float a0 = ga[j];
        float4 g1 = gc[j + 4]; float a1 = ga[j + 4];
        float u = iou_pair(px0, py0, px1, py1, pa, g0.x, g0.y, g0.z, g0.w, a0);
        float w = iou_pair(px0, py0, px1, py1, pa, g1.x, g1.y, g1.z, g1.w, a1);
        if (u > vA){ vA = u; jA = j; }
        if (w > vB){ vB = w; jB = j + 4; }
      }
      if (j < n2){
        float4 g0 = gc[j]; float a0 = ga[j];
        float u = iou_pair(px0, py0, px1, py1, pa, g0.x, g0.y, g0.z, g0.w, a0);
        if (u > vA){ vA = u; jA = j; }
      }
    }
    if (vB > vA || (vB == vA && jB < jA)){ vA = vB; jA = jB; }
    #pragma unroll
    for (int m = 1; m <= 2; m <<= 1){
      float ov = __shfl_xor(vA, m, 64);
      int   oj = __shfl_xor(jA, m, 64);
      if (ov > vA || (ov == vA && oj < jA)){ vA = ov; jA = oj; }
    }
    if (valid && q == 0){
      max_iou[lo + pi] = vA;
      input_idx[lo + pi] = jA;
      pc[pi] = make_float4(px0, py0, px1, py1);
      pa_s[pi] = pa;
    }
  }
  __syncthreads();

  // col pass: thread t owns GTs t and t+256 (2 independent chains);
  // pc[p] is wave-uniform -> LDS broadcast. Strict > ascending p = first max.
  {
    float4 g1 = make_float4(0,0,0,0), g2 = make_float4(0,0,0,0);
    float a1 = 0, a2 = 0;
    const bool v1 = (t < n2), v2 = (t + TPB < n2);
    if (v1){ g1 = gc[t];       a1 = ga[t]; }
    if (v2){ g2 = gc[t + TPB]; a2 = ga[t + TPB]; }
    float cv1 = -1.0f, cv2 = -1.0f; int ci1 = 0, ci2 = 0;
    for (int p = 0; p < cr; ++p){
      float4 pv = pc[p]; float pav = pa_s[p];
      float u = iou_pair(pv.x, pv.y, pv.z, pv.w, pav, g1.x, g1.y, g1.z, g1.w, a1);
      float w = iou_pair(pv.x, pv.y, pv.z, pv.w, pav, g2.x, g2.y, g2.z, g2.w, a2);
      if (u > cv1){ cv1 = u; ci1 = p; }
      if (w > cv2){ cv2 = w; ci2 = p; }
    }
    // key: bits(nonneg IoU)<<32 | ~globalIdx -> max = best val, tie lowest idx
    if (v1) colpart[(size_t)b * n2 + t] =
      ((ull)__float_as_uint(cv1) << 32) | (ull)(unsigned)~(unsigned)(lo + ci1);
    if (v2) colpart[(size_t)b * n2 + t + TPB] =
      ((ull)__float_as_uint(cv2) << 32) | (ull)(unsigned)~(unsigned)(lo + ci2);
  }
}

// ---- K2: per-GT reduce over block partials + forced scatter ----
__global__ __launch_bounds__(TPB)
void colreduce(const ull* __restrict__ colpart, int n2, int nblk,
               unsigned char* __restrict__ forced)
{
  const int jj = blockIdx.x, t = threadIdx.x;
  ull m = 0;
  for (int x = t; x < nblk; x += TPB){
    ull v = colpart[(size_t)x * n2 + jj];
    if (v > m) m = v;
  }
  __shared__ ull red[TPB];
  red[t] = m;
  __syncthreads();
  for (int s = TPB >> 1; s > 0; s >>= 1){
    if (t < s && red[t + s] > red[t]) red[t] = red[t + s];
    __syncthreads();
  }
  if (t == 0) forced[~(unsigned)(red[0] & 0xFFFFFFFFull)] = 1;
}

// ---- K3: per-mode block: exact counts -> adaptive-ladder collect -> rank-select ----
__global__ __launch_bounds__(1024)
void final_kernel(const float* __restrict__ max_iou, const unsigned char* __restrict__ forced,
                  const float* __restrict__ pn, const float* __restrict__ nn,
                  int n1, const int* __restrict__ input_idx, int* __restrict__ out)
{
  const int t = threadIdx.x;
  const bool isPos = (blockIdx.x == 0);
  __shared__ ull keys[CAP];
  __shared__ int s_cnt, s_a, s_b, s_lad[NLAD];
  __shared__ float s_tau;

  // ---- pass A: exact mask counts (normal mask; for neg also fallback mask)
  if (t == 0){ s_a = 0; s_b = 0; }
  if (t < NLAD) s_lad[t] = 0;
  __syncthreads();
  int ca = 0, cb = 0;
  for (int i = t; i < n1; i += 1024){
    float m = max_iou[i];
    bool f = forced[i] != 0;
    bool pos = (m > HIGHT) || f;
    if (isPos) ca += pos ? 1 : 0;
    else { ca += ((m < LOWT) && !f) ? 1 : 0; cb += (!pos) ? 1 : 0; }
  }
  #pragma unroll
  for (int o = 32; o > 0; o >>= 1){ ca += __shfl_down(ca, o, 64); cb += __shfl_down(cb, o, 64); }
  if ((t & 63) == 0){ if (ca) atomicAdd(&s_a, ca); if (cb) atomicAdd(&s_b, cb); }
  __syncthreads();
  const bool fb = (!isPos && s_a == 0);          // no negatives -> complement of pos
  const int tot = isPos ? s_a : (fb ? s_b : s_a);
  const bool all = (tot <= CAP);

  // ---- pass B (only when mask > CAP): exact counts above each ladder level.
  // Picks the largest tau with count >= KSEL: collected then provably contains
  // the true top-128; for iid-uniform noise adjacent-level survival ratios
  // (<=5) keep the chosen count << CAP.
  if (!all){
    for (int i = t; i < n1; i += 1024){
      float m = max_iou[i];
      bool f = forced[i] != 0;
      bool pos = (m > HIGHT) || f;
      bool sel = isPos ? pos : (fb ? !pos : ((m < LOWT) && !f));
      float sc = sel ? (isPos ? pn[i] : nn[i]) : -1.0f;
      ull b0 = __ballot(sc > 0.998f);
      ull b1 = __ballot(sc > 0.99f);
      ull b2 = __ballot(sc > 0.95f);
      ull b3 = __ballot(sc > 0.8f);
      ull b4 = __ballot(sc > 0.5f);
      ull b5 = __ballot(sc > 0.25f);
      ull b6 = __ballot(sc > 0.0625f);
      if ((t & 63) == 0){
        if (b0) atomicAdd(&s_lad[0], __popcll(b0));
        if (b1) atomicAdd(&s_lad[1], __popcll(b1));
        if (b2) atomicAdd(&s_lad[2], __popcll(b2));
        if (b3) atomicAdd(&s_lad[3], __popcll(b3));
        if (b4) atomicAdd(&s_lad[4], __popcll(b4));
        if (b5) atomicAdd(&s_lad[5], __popcll(b5));
        if (b6) atomicAdd(&s_lad[6], __popcll(b6));
      }
    }
  }
  __syncthreads();
  if (t == 0){
    s_cnt = 0;
    float tau = -1.0f;                            // default: collect all masked
    if (!all){
      const float L[NLAD] = {0.998f, 0.99f, 0.95f, 0.8f, 0.5f, 0.25f, 0.0625f};
      for (int k = 0; k < NLAD; ++k){
        if (s_lad[k] >= KSEL){ tau = L[k]; break; }
      }
    }
    s_tau = tau;
  }
  __syncthreads();
  const float tau = s_tau;

  // ---- pass C: collect. Key: (bits(score)+1)<<32 | ~i  (score in [0,1) ->
  // bits monotone; +1 so the -1-score fill key (0) loses to a real 0.0 score).
  for (int i = t; i < n1; i += 1024){
    float m = max_iou[i];
    bool f = forced[i] != 0;
    bool pos = (m > HIGHT) || f;
    bool sel = isPos ? pos : (fb ? !pos : ((m < LOWT) && !f));
    if (sel){
      float sc = isPos ? pn[i] : nn[i];
      if (sc > tau){
        unsigned k32 = __float_as_uint(sc) + 1u;
        int p = atomicAdd(&s_cnt, 1);
        if (p < CAP) keys[p] = ((ull)k32 << 32) | (ull)(unsigned)~(unsigned)i;
      }
    } else if (tot < KSEL && i < 2 * KSEL){
      // fewer than 128 real candidates: ref top_k fills with -1-scored entries
      // in ascending index; all needed fills have index < 2*KSEL
      int p = atomicAdd(&s_cnt, 1);
      if (p < CAP) keys[p] = (ull)(unsigned)~(unsigned)i;   // k32 = 0
    }
  }
  __syncthreads();
  int n = s_cnt; if (n > CAP) n = CAP;

  // ---- exact rank-select (keys totally ordered & unique)
  ull mk[2]; int mr[2]; int ne = 0;
  for (int x = t; x < n; x += 1024){ mk[ne] = keys[x]; mr[ne] = 0; ++ne; }
  for (int o = 0; o < n; ++o){
    ull ko = keys[o];                             // uniform addr -> LDS broadcast
    if (ne > 0) mr[0] += (ko > mk[0]);
    if (ne > 1) mr[1] += (ko > mk[1]);
  }
  for (int e = 0; e < ne; ++e){
    int r = mr[e];
    if (r < KSEL){
      unsigned idx = ~(unsigned)(mk[e] & 0xFFFFFFFFull);
      if (isPos){ out[r] = (int)idx; out[KSEL + r] = input_idx[idx]; }
      else        out[2 * KSEL + r] = (int)idx;
    }
  }
}

extern "C" void kernel_launch(void* const* d_in, const int* in_sizes, int n_in,
                              void* d_out, int out_size, void* d_ws, size_t ws_size,
                              hipStream_t stream){
  const float4* boxes = (const float4*)d_in[0];
  const float4* gts   = (const float4*)d_in[1];
  const float* pos_noise = (const float*)d_in[2];
  const float* neg_noise = (const float*)d_in[3];
  const int n1 = in_sizes[0] / 4;
  const int n2 = in_sizes[1] / 4;
  int* out = (int*)d_out;

  char* ws = (char*)d_ws;
  size_t off = 0;
  auto carve = [&](size_t bytes) -> char* {
    char* p = ws + off;
    off = (off + bytes + 255) & ~(size_t)255;
    return p;
  };
  const int nblk = (n1 + CHUNK - 1) / CHUNK;       // 782
  float* max_iou   = (float*)carve((size_t)n1 * 4);
  int*   input_idx = (int*)  carve((size_t)n1 * 4);
  ull*   colpart   = (ull*)  carve((size_t)nblk * n2 * 8);
  unsigned char* forced = (unsigned char*)carve(((size_t)n1 + 3) & ~(size_t)3);

  fused_iou<<<nblk, TPB, 0, stream>>>(boxes, gts, n1, n2, nblk,
                                      max_iou, input_idx, colpart, (unsigned*)forced);
  colreduce<<<n2, TPB, 0, stream>>>(colpart, n2, nblk, forced);
  final_kernel<<<2, 1024, 0, stream>>>(max_iou, forced, pos_noise, neg_noise,
                                       n1, input_idx, out);
}

// Round 8
// 149.175 us; speedup vs baseline: 3.7437x; 1.3702x over previous
//
#include <hip/hip_runtime.h>
#include <stdint.h>

#pragma clang fp contract(off)

typedef unsigned long long ull;

#define HIGHT 0.7f
#define LOWT  0.3f
#define KSEL  128
#define CAP   2048         // candidate buffer per mode
#define MAXGT 512
#define TPB   256
#define CHUNK 64           // proposals per fused_iou block
#define NLAD  7            // adaptive threshold ladder

// counter layout (int cnts[32] in ws):
// [0] posMask  [1] negMask(normal)  [2] notPos
// [3..9] pos ladder  [10..16] neg-normal ladder  [17..23] neg-fallback ladder
// [24] collect cnt pos   [25] collect cnt neg
__device__ __constant__ float LADV[NLAD] = {0.998f, 0.99f, 0.95f, 0.8f, 0.5f, 0.25f, 0.0625f};

// ---- bit-exact IoU (numpy fp32 op-for-op; no contraction; IEEE div) ----
__device__ __forceinline__ float iou_pair(float ax0, float ay0, float ax1, float ay1, float aarea,
                                          float bx0, float by0, float bx1, float by1, float barea){
#pragma clang fp contract(off)
  float x0 = fmaxf(ax0, bx0);
  float y0 = fmaxf(ay0, by0);
  float x1 = fminf(ax1, bx1);
  float y1 = fminf(ay1, by1);
  float dx = fmaxf(x1 - x0, 0.0f);
  float dy = fmaxf(y1 - y0, 0.0f);
  float inter = dx * dy;
  float uni = (aarea + barea) - inter;
  return inter / uni;
}

// ---- K1: zero scratch + row max/argmax + col partials (corners staged in LDS) ----
__global__ __launch_bounds__(TPB)
void fused_iou(const float4* __restrict__ boxes, const float4* __restrict__ gts,
               int n1, int n2, int nblk,
               float* __restrict__ max_iou, int* __restrict__ input_idx,
               ull* __restrict__ colpart, unsigned* __restrict__ forcedw,
               int* __restrict__ cnts)
{
#pragma clang fp contract(off)
  const int b = blockIdx.x, t = threadIdx.x;

  // distributed zeroing (consumed by later kernels; stream order suffices)
  {
    const int fw = (n1 + 3) >> 2;
    for (int x = b * TPB + t; x < fw; x += nblk * TPB) forcedw[x] = 0u;
    if (b == 0 && t < 32) cnts[t] = 0;
  }

  __shared__ float4 gc[MAXGT];
  __shared__ float  ga[MAXGT];
  __shared__ float4 pc[CHUNK];
  __shared__ float  pa_s[CHUNK];

  for (int j = t; j < n2; j += TPB){
    float4 g = gts[j];
    float hw = g.z * 0.5f, hh = g.w * 0.5f;
    gc[j] = make_float4(g.x - hw, g.y - hh, g.x + hw, g.y + hh);
    ga[j] = g.z * g.w;
  }
  __syncthreads();

  const int lo = b * CHUNK;
  int cr = n1 - lo; if (cr > CHUNK) cr = CHUNK; if (cr < 0) cr = 0;

  // row pass: 4 threads/proposal, quarter q owns j = q, q+4, ...; TWO
  // independent chains (j, j+4 step 8) to overlap div latency. IoU >= 0,
  // never NaN; strict > with ascending j = first-occurrence argmax.
  {
    const int pi = t >> 2, q = t & 3;
    const bool valid = (pi < cr);
    float vA = -1.0f, vB = -1.0f; int jA = 0, jB = 0;
    float px0 = 0, py0 = 0, px1 = 0, py1 = 0, pa = 0;
    if (valid){
      float4 pb = boxes[lo + pi];
      float hw = pb.z * 0.5f, hh = pb.w * 0.5f;
      px0 = pb.x - hw; py0 = pb.y - hh; px1 = pb.x + hw; py1 = pb.y + hh;
      pa = pb.z * pb.w;
      int j = q;
      for (; j + 4 < n2; j += 8){
        float4 g0 = gc[j];     float a0 = ga[j];
        float4 g1 = gc[j + 4]; float a1 = ga[j + 4];
        float u = iou_pair(px0, py0, px1, py1, pa, g0.x, g0.y, g0.z, g0.w, a0);
        float w = iou_pair(px0, py0, px1, py1, pa, g1.x, g1.y, g1.z, g1.w, a1);
        if (u > vA){ vA = u; jA = j; }
        if (w > vB){ vB = w; jB = j + 4; }
      }
      if (j < n2){
        float4 g0 = gc[j]; float a0 = ga[j];
        float u = iou_pair(px0, py0, px1, py1, pa, g0.x, g0.y, g0.z, g0.w, a0);
        if (u > vA){ vA = u; jA = j; }
      }
    }
    if (vB > vA || (vB == vA && jB < jA)){ vA = vB; jA = jB; }
    #pragma unroll
    for (int m = 1; m <= 2; m <<= 1){
      float ov = __shfl_xor(vA, m, 64);
      int   oj = __shfl_xor(jA, m, 64);
      if (ov > vA || (ov == vA && oj < jA)){ vA = ov; jA = oj; }
    }
    if (valid && q == 0){
      max_iou[lo + pi] = vA;
      input_idx[lo + pi] = jA;
      pc[pi] = make_float4(px0, py0, px1, py1);
      pa_s[pi] = pa;
    }
  }
  __syncthreads();

  // col pass: thread t owns GTs t and t+256 (2 independent chains);
  // pc[p] is wave-uniform -> LDS broadcast. Strict > ascending p = first max.
  {
    float4 g1 = make_float4(0,0,0,0), g2 = make_float4(0,0,0,0);
    float a1 = 0, a2 = 0;
    const bool v1 = (t < n2), v2 = (t + TPB < n2);
    if (v1){ g1 = gc[t];       a1 = ga[t]; }
    if (v2){ g2 = gc[t + TPB]; a2 = ga[t + TPB]; }
    float cv1 = -1.0f, cv2 = -1.0f; int ci1 = 0, ci2 = 0;
    for (int p = 0; p < cr; ++p){
      float4 pv = pc[p]; float pav = pa_s[p];
      float u = iou_pair(pv.x, pv.y, pv.z, pv.w, pav, g1.x, g1.y, g1.z, g1.w, a1);
      float w = iou_pair(pv.x, pv.y, pv.z, pv.w, pav, g2.x, g2.y, g2.z, g2.w, a2);
      if (u > cv1){ cv1 = u; ci1 = p; }
      if (w > cv2){ cv2 = w; ci2 = p; }
    }
    // key: bits(nonneg IoU)<<32 | ~globalIdx -> max = best val, tie lowest idx
    if (v1) colpart[(size_t)b * n2 + t] =
      ((ull)__float_as_uint(cv1) << 32) | (ull)(unsigned)~(unsigned)(lo + ci1);
    if (v2) colpart[(size_t)b * n2 + t + TPB] =
      ((ull)__float_as_uint(cv2) << 32) | (ull)(unsigned)~(unsigned)(lo + ci2);
  }
}

// ---- K2: per-GT reduce over block partials + forced scatter ----
__global__ __launch_bounds__(TPB)
void colreduce(const ull* __restrict__ colpart, int n2, int nblk,
               unsigned char* __restrict__ forced)
{
  const int jj = blockIdx.x, t = threadIdx.x;
  ull m = 0;
  for (int x = t; x < nblk; x += TPB){
    ull v = colpart[(size_t)x * n2 + jj];
    if (v > m) m = v;
  }
  __shared__ ull red[TPB];
  red[t] = m;
  __syncthreads();
  for (int s = TPB >> 1; s > 0; s >>= 1){
    if (t < s && red[t + s] > red[t]) red[t] = red[t + s];
    __syncthreads();
  }
  if (t == 0) forced[~(unsigned)(red[0] & 0xFFFFFFFFull)] = 1;
}

// ---- K3: grid-wide exact counts: masks + 3x7 ladder (ballot -> LDS -> global) ----
__global__ __launch_bounds__(TPB)
void count_kernel(const float* __restrict__ max_iou, const unsigned char* __restrict__ forced,
                  const float* __restrict__ pn, const float* __restrict__ nn,
                  int n1, int* __restrict__ cnts)
{
  __shared__ int lc[24];
  const int t = threadIdx.x;
  if (t < 24) lc[t] = 0;
  __syncthreads();
  const int i = blockIdx.x * TPB + t;
  bool pos = false, nm = false, np = false;
  float sp = -1.0f, sn = -1.0f;
  if (i < n1){
    float m = max_iou[i];
    bool f = forced[i] != 0;
    pos = (m > HIGHT) || f;
    nm = (m < LOWT) && !f;
    np = !pos;
    if (pos) sp = pn[i];
    float ni = nn[i];
    if (nm || np) sn = ni;
  }
  const bool lead = ((t & 63) == 0);
  ull bl;
  bl = __ballot(pos); if (lead && bl) atomicAdd(&lc[0], __popcll(bl));
  bl = __ballot(nm);  if (lead && bl) atomicAdd(&lc[1], __popcll(bl));
  bl = __ballot(np);  if (lead && bl) atomicAdd(&lc[2], __popcll(bl));
  #pragma unroll
  for (int k = 0; k < NLAD; ++k){
    float L = LADV[k];
    bl = __ballot(pos && sp > L); if (lead && bl) atomicAdd(&lc[3 + k], __popcll(bl));
    bl = __ballot(nm  && sn > L); if (lead && bl) atomicAdd(&lc[10 + k], __popcll(bl));
    bl = __ballot(np  && sn > L); if (lead && bl) atomicAdd(&lc[17 + k], __popcll(bl));
  }
  __syncthreads();
  if (t < 24 && lc[t]) atomicAdd(&cnts[t], lc[t]);
}

// ---- tau from ladder: largest level with >= KSEL survivors (exact superset) ----
__device__ __forceinline__ float pick_tau(const int* lad, int tot){
  if (tot <= CAP) return -1.0f;          // collect all masked (exact, covers fill)
  for (int k = 0; k < NLAD; ++k)
    if (lad[k] >= KSEL) return LADV[k];
  return -1.0f;
}

// ---- K4: grid-wide collect into global cand buffers ----
__global__ __launch_bounds__(TPB)
void collect_kernel(const float* __restrict__ max_iou, const unsigned char* __restrict__ forced,
                    const float* __restrict__ pn, const float* __restrict__ nn,
                    int n1, int* __restrict__ cnts, ull* __restrict__ cand)
{
  __shared__ int s_c[24];
  const int t = threadIdx.x;
  if (t < 24) s_c[t] = cnts[t];
  __syncthreads();
  const bool fb = (s_c[1] == 0);                 // no negatives -> complement of pos
  const int totP = s_c[0];
  const int totN = fb ? s_c[2] : s_c[1];
  const float tauP = pick_tau(&s_c[3], totP);
  const float tauN = pick_tau(fb ? &s_c[17] : &s_c[10], totN);

  const int i = blockIdx.x * TPB + t;
  if (i >= n1) return;
  float m = max_iou[i];
  bool f = forced[i] != 0;
  bool pos = (m > HIGHT) || f;
  // pos mode. Key: (bits(score)+1)<<32 | ~i  (score in [0,1) -> bits monotone;
  // +1 so the fill key (k32=0) loses to a real 0.0 score).
  if (pos){
    float sc = pn[i];
    if (sc > tauP){
      int p = atomicAdd(&cnts[24], 1);
      if (p < CAP) cand[p] = ((ull)(__float_as_uint(sc) + 1u) << 32) | (ull)(unsigned)~(unsigned)i;
    }
  } else if (totP < KSEL && i < 2 * KSEL){
    // ref top_k fills with -1-scored entries in ascending index; all needed
    // fills have index < 2*KSEL
    int p = atomicAdd(&cnts[24], 1);
    if (p < CAP) cand[p] = (ull)(unsigned)~(unsigned)i;
  }
  // neg mode
  bool seln = fb ? (!pos) : ((m < LOWT) && !f);
  if (seln){
    float sc = nn[i];
    if (sc > tauN){
      int p = atomicAdd(&cnts[25], 1);
      if (p < CAP) cand[CAP + p] = ((ull)(__float_as_uint(sc) + 1u) << 32) | (ull)(unsigned)~(unsigned)i;
    }
  } else if (totN < KSEL && i < 2 * KSEL){
    int p = atomicAdd(&cnts[25], 1);
    if (p < CAP) cand[CAP + p] = (ull)(unsigned)~(unsigned)i;
  }
}

// ---- K5: exact rank-select of top-128 per mode (keys totally ordered, unique) ----
__global__ __launch_bounds__(1024)
void select_kernel(const ull* __restrict__ cand, const int* __restrict__ cnts,
                   const int* __restrict__ input_idx, int* __restrict__ out)
{
  const int t = threadIdx.x;
  const bool isPos = (blockIdx.x == 0);
  __shared__ ull keys[CAP];
  int n = cnts[isPos ? 24 : 25]; if (n > CAP) n = CAP;
  for (int x = t; x < n; x += 1024)
    keys[x] = cand[(isPos ? 0 : CAP) + x];
  __syncthreads();
  ull mk[2]; int mr[2]; int ne = 0;
  for (int x = t; x < n; x += 1024){ mk[ne] = keys[x]; mr[ne] = 0; ++ne; }
  for (int o = 0; o < n; ++o){
    ull ko = keys[o];                             // uniform addr -> LDS broadcast
    if (ne > 0) mr[0] += (ko > mk[0]);
    if (ne > 1) mr[1] += (ko > mk[1]);
  }
  for (int e = 0; e < ne; ++e){
    int r = mr[e];
    if (r < KSEL){
      unsigned idx = ~(unsigned)(mk[e] & 0xFFFFFFFFull);
      if (isPos){ out[r] = (int)idx; out[KSEL + r] = input_idx[idx]; }
      else        out[2 * KSEL + r] = (int)idx;
    }
  }
}

extern "C" void kernel_launch(void* const* d_in, const int* in_sizes, int n_in,
                              void* d_out, int out_size, void* d_ws, size_t ws_size,
                              hipStream_t stream){
  const float4* boxes = (const float4*)d_in[0];
  const float4* gts   = (const float4*)d_in[1];
  const float* pos_noise = (const float*)d_in[2];
  const float* neg_noise = (const float*)d_in[3];
  const int n1 = in_sizes[0] / 4;
  const int n2 = in_sizes[1] / 4;
  int* out = (int*)d_out;

  char* ws = (char*)d_ws;
  size_t off = 0;
  auto carve = [&](size_t bytes) -> char* {
    char* p = ws + off;
    off = (off + bytes + 255) & ~(size_t)255;
    return p;
  };
  const int nblk = (n1 + CHUNK - 1) / CHUNK;       // 782
  float* max_iou   = (float*)carve((size_t)n1 * 4);
  int*   input_idx = (int*)  carve((size_t)n1 * 4);
  ull*   colpart   = (ull*)  carve((size_t)nblk * n2 * 8);
  unsigned char* forced = (unsigned char*)carve(((size_t)n1 + 3) & ~(size_t)3);
  int*   cnts      = (int*)  carve(32 * 4);
  ull*   cand      = (ull*)  carve((size_t)2 * CAP * 8);

  const int gb = (n1 + TPB - 1) / TPB;             // 196
  fused_iou<<<nblk, TPB, 0, stream>>>(boxes, gts, n1, n2, nblk,
                                      max_iou, input_idx, colpart,
                                      (unsigned*)forced, cnts);
  colreduce<<<n2, TPB, 0, stream>>>(colpart, n2, nblk, forced);
  count_kernel<<<gb, TPB, 0, stream>>>(max_iou, forced, pos_noise, neg_noise, n1, cnts);
  collect_kernel<<<gb, TPB, 0, stream>>>(max_iou, forced, pos_noise, neg_noise, n1, cnts, cand);
  select_kernel<<<2, 1024, 0, stream>>>(cand, cnts, input_idx, out);
}